// Round 1
// baseline (748.850 us; speedup 1.0000x reference)
//
#include <hip/hip_runtime.h>
#include <hip/hip_bf16.h>

#define N_ 50000
#define E_ 800000
#define D_ 128
#define L_ 3

// ---------------- CSR build ----------------

__global__ void k_count(const int* __restrict__ dst, int* __restrict__ deg) {
    int e = blockIdx.x * 256 + threadIdx.x;
    if (e < E_) atomicAdd(&deg[dst[e]], 1);
}

__global__ void k_dis(const int* __restrict__ deg, float* __restrict__ dis) {
    int i = blockIdx.x * 256 + threadIdx.x;
    if (i < N_) dis[i] = rsqrtf((float)deg[i] + 1.0f);
}

// single-block exclusive scan of deg -> row_ptr  (N=50000, 1024 threads x 49 chunk)
__global__ __launch_bounds__(1024) void k_scan(const int* __restrict__ deg,
                                               int* __restrict__ row_ptr) {
    __shared__ int a[1024];
    int t = threadIdx.x;
    const int CH = 49;
    int base = t * CH;
    int s = 0;
    for (int j = 0; j < CH; ++j) { int idx = base + j; if (idx < N_) s += deg[idx]; }
    a[t] = s;
    __syncthreads();
    // Hillis-Steele inclusive scan over 1024 partials
    for (int off = 1; off < 1024; off <<= 1) {
        int v = (t >= off) ? a[t - off] : 0;
        __syncthreads();
        a[t] += v;
        __syncthreads();
    }
    int run = a[t] - s;  // exclusive prefix for this thread's chunk
    for (int j = 0; j < CH; ++j) {
        int idx = base + j;
        if (idx < N_) { row_ptr[idx] = run; run += deg[idx]; }
    }
    if (t == 0) row_ptr[N_] = E_;
}

__global__ void k_fill(const int* __restrict__ src, const int* __restrict__ dst,
                       const int* __restrict__ row_ptr, int* __restrict__ cursor,
                       int* __restrict__ csr_src) {
    int e = blockIdx.x * 256 + threadIdx.x;
    if (e < E_) {
        int d = dst[e];
        int pos = row_ptr[d] + atomicAdd(&cursor[d], 1);
        csr_src[pos] = src[e];
    }
}

// ---------------- GEMM: H = X @ W  (fp32, LDS-tiled, 64 rows x 128 cols / block) ----------------

__global__ __launch_bounds__(256) void k_gemm(const float* __restrict__ X,
                                              const float* __restrict__ W,
                                              float* __restrict__ H) {
    __shared__ float wlds[32 * 128];   // K-chunk of W: 16 KB
    __shared__ float xlds[64 * 36];    // 64 rows x 32 k, padded stride 36: 9 KB
    int t  = threadIdx.x;
    int r0 = blockIdx.x * 64;
    int cg = t & 15;    // col group: 8 cols each
    int rg = t >> 4;    // row group: 4 rows each

    float acc[4][8];
#pragma unroll
    for (int j = 0; j < 4; ++j)
#pragma unroll
        for (int c = 0; c < 8; ++c) acc[j][c] = 0.f;

    for (int k0 = 0; k0 < 128; k0 += 32) {
        // stage W[k0..k0+32][0..128): 1024 float4, 4 per thread, coalesced
#pragma unroll
        for (int j = 0; j < 4; ++j) {
            int f = t + 256 * j;
            ((float4*)wlds)[f] = ((const float4*)(W + k0 * 128))[f];
        }
        // stage X[r0..r0+64][k0..k0+32): 512 float4, 2 per thread
#pragma unroll
        for (int j = 0; j < 2; ++j) {
            int g   = t + 256 * j;
            int row = g >> 3;
            int kk4 = (g & 7) * 4;
            int gr  = r0 + row;
            float4 v = make_float4(0.f, 0.f, 0.f, 0.f);
            if (gr < N_) v = *(const float4*)(X + gr * 128 + k0 + kk4);
            xlds[row * 36 + kk4 + 0] = v.x;
            xlds[row * 36 + kk4 + 1] = v.y;
            xlds[row * 36 + kk4 + 2] = v.z;
            xlds[row * 36 + kk4 + 3] = v.w;
        }
        __syncthreads();
#pragma unroll
        for (int kk = 0; kk < 32; ++kk) {
            float4 w0 = *(const float4*)(wlds + kk * 128 + cg * 8);
            float4 w1 = *(const float4*)(wlds + kk * 128 + cg * 8 + 4);
#pragma unroll
            for (int j = 0; j < 4; ++j) {
                float xv = xlds[(rg * 4 + j) * 36 + kk];
                acc[j][0] += xv * w0.x; acc[j][1] += xv * w0.y;
                acc[j][2] += xv * w0.z; acc[j][3] += xv * w0.w;
                acc[j][4] += xv * w1.x; acc[j][5] += xv * w1.y;
                acc[j][6] += xv * w1.z; acc[j][7] += xv * w1.w;
            }
        }
        __syncthreads();
    }
#pragma unroll
    for (int j = 0; j < 4; ++j) {
        int r = r0 + rg * 4 + j;
        if (r < N_) {
            *(float4*)(H + r * 128 + cg * 8)     = make_float4(acc[j][0], acc[j][1], acc[j][2], acc[j][3]);
            *(float4*)(H + r * 128 + cg * 8 + 4) = make_float4(acc[j][4], acc[j][5], acc[j][6], acc[j][7]);
        }
    }
}

// ---------------- Aggregation: AGG[n] = dn * sum_e dis[s]*H[s] + dn*dn*H[n] + b ----------------

__global__ __launch_bounds__(128) void k_agg(const float* __restrict__ H,
                                             const int* __restrict__ row_ptr,
                                             const int* __restrict__ csr_src,
                                             const float* __restrict__ dis,
                                             const float* __restrict__ bias,
                                             float* __restrict__ AGG) {
    int n = blockIdx.x;
    int t = threadIdx.x;       // feature
    int beg = row_ptr[n], end = row_ptr[n + 1];
    float dn = dis[n];
    float sum = 0.f;
    for (int j = beg; j < end; ++j) {
        int s = csr_src[j];
        sum += dis[s] * H[s * 128 + t];
    }
    AGG[n * 128 + t] = dn * sum + dn * dn * H[n * 128 + t] + bias[t];
}

// ---------------- BatchNorm stats: per-feature sum & sumsq ----------------

__global__ __launch_bounds__(256) void k_stats(const float* __restrict__ AGG,
                                               float* __restrict__ stats) {
    int f    = threadIdx.x & 127;
    int half = threadIdx.x >> 7;
    float s = 0.f, s2 = 0.f;
    for (int r = blockIdx.x * 2 + half; r < N_; r += gridDim.x * 2) {
        float v = AGG[r * 128 + f];
        s += v; s2 += v * v;
    }
    __shared__ float ls[256], ls2[256];
    ls[threadIdx.x] = s; ls2[threadIdx.x] = s2;
    __syncthreads();
    if (half == 0) {
        s  = ls[f]  + ls[128 + f];
        s2 = ls2[f] + ls2[128 + f];
        atomicAdd(&stats[f], s);
        atomicAdd(&stats[128 + f], s2);
    }
}

__global__ void k_bnfinal(const float* __restrict__ stats,
                          const float* __restrict__ gamma,
                          const float* __restrict__ beta,
                          float* __restrict__ ab) {
    int f = threadIdx.x;  // 128
    float mean = stats[f] * (1.0f / N_);
    float var  = stats[128 + f] * (1.0f / N_) - mean * mean;
    float a = gamma[f] * rsqrtf(var + 1e-5f);
    ab[f]       = a;
    ab[128 + f] = beta[f] - mean * a;
}

// ---------------- Normalize + ReLU + residual (float4) ----------------

__global__ __launch_bounds__(256) void k_norm(const float* __restrict__ AGG,
                                              const float* __restrict__ res,
                                              const float* __restrict__ ab,
                                              float* __restrict__ OUT,
                                              int relu) {
    int i = blockIdx.x * 256 + threadIdx.x;  // float4 index
    if (i >= N_ * 32) return;
    int f4 = (i & 31) * 4;
    float4 v = ((const float4*)AGG)[i];
    float a0 = ab[f4], a1 = ab[f4 + 1], a2 = ab[f4 + 2], a3 = ab[f4 + 3];
    float b0 = ab[128 + f4], b1 = ab[128 + f4 + 1], b2 = ab[128 + f4 + 2], b3 = ab[128 + f4 + 3];
    v.x = a0 * v.x + b0; v.y = a1 * v.y + b1; v.z = a2 * v.z + b2; v.w = a3 * v.w + b3;
    if (relu) {
        v.x = fmaxf(v.x, 0.f); v.y = fmaxf(v.y, 0.f);
        v.z = fmaxf(v.z, 0.f); v.w = fmaxf(v.w, 0.f);
    }
    if (res) {
        float4 r = ((const float4*)res)[i];
        v.x += r.x; v.y += r.y; v.z += r.z; v.w += r.w;
    }
    ((float4*)OUT)[i] = v;
}

// ---------------- Launch ----------------

extern "C" void kernel_launch(void* const* d_in, const int* in_sizes, int n_in,
                              void* d_out, int out_size, void* d_ws, size_t ws_size,
                              hipStream_t stream) {
    const float* x      = (const float*)d_in[0];
    const int*   ei     = (const int*)d_in[1];
    const float* Ws     = (const float*)d_in[2];
    const float* bs     = (const float*)d_in[3];
    const float* gammas = (const float*)d_in[4];
    const float* betas  = (const float*)d_in[5];
    float* out = (float*)d_out;

    const int* src = ei;
    const int* dst = ei + E_;

    char* w = (char*)d_ws;
    // layout (byte offsets; all 16B-aligned)
    int*   deg_int = (int*)(w + 0);                 // N ints
    int*   cursor  = (int*)(w + 200000);            // N ints
    float* stats   = (float*)(w + 400000);          // L*2*D floats
    float* ab      = (float*)(w + 403072);          // 2*D floats
    int*   row_ptr = (int*)(w + 404096);            // N+1 ints
    float* dis     = (float*)(w + 604112);          // N floats
    int*   csr_src = (int*)(w + 804112);            // E ints
    float* B1      = (float*)(w + 4004112);         // N*D floats
    float* B2      = (float*)(w + 29604112);        // N*D floats

    // zero deg_int + cursor + stats (contiguous region [0, 403072))
    hipMemsetAsync(d_ws, 0, 403072, stream);

    k_count<<<(E_ + 255) / 256, 256, 0, stream>>>(dst, deg_int);
    k_dis<<<(N_ + 255) / 256, 256, 0, stream>>>(deg_int, dis);
    k_scan<<<1, 1024, 0, stream>>>(deg_int, row_ptr);
    k_fill<<<(E_ + 255) / 256, 256, 0, stream>>>(src, dst, row_ptr, cursor, csr_src);

    // buffer rotation:
    // L0: gemm(x    ->B1), agg(B1->B2),  stats(B2),  norm(B2, null -> out), relu
    // L1: gemm(out  ->B1), agg(B1->B2),  stats(B2),  norm(B2, out  -> B1),  relu
    // L2: gemm(B1   ->B2), agg(B2->out), stats(out), norm(out, B1  -> out), no relu
    const float* gemm_in[3]  = { x, out, B1 };
    float*       gemm_out[3] = { B1, B1, B2 };
    float*       agg_out[3]  = { B2, B2, out };
    const float* norm_res[3] = { nullptr, out, B1 };
    float*       norm_out[3] = { out, B1, out };
    int          relu[3]     = { 1, 1, 0 };

    for (int i = 0; i < L_; ++i) {
        k_gemm<<<(N_ + 63) / 64, 256, 0, stream>>>(gemm_in[i], Ws + i * D_ * D_, gemm_out[i]);
        k_agg<<<N_, 128, 0, stream>>>(gemm_out[i], row_ptr, csr_src, dis, bs + i * D_, agg_out[i]);
        k_stats<<<256, 256, 0, stream>>>(agg_out[i], stats + i * 2 * D_);
        k_bnfinal<<<1, 128, 0, stream>>>(stats + i * 2 * D_, gammas + i * D_, betas + i * D_, ab);
        k_norm<<<(N_ * 32 + 255) / 256, 256, 0, stream>>>(agg_out[i], norm_res[i], ab, norm_out[i], relu[i]);
    }
}

// Round 2
// 513.025 us; speedup vs baseline: 1.4597x; 1.4597x over previous
//
#include <hip/hip_runtime.h>
#include <hip/hip_bf16.h>

#define N_ 50000
#define E_ 800000
#define D_ 128
#define L_ 3

// ---------------- helpers ----------------

__device__ inline float4 bcvt(uint2 u) {   // 4 packed bf16 -> float4
    float4 r;
    r.x = __uint_as_float(u.x << 16);
    r.y = __uint_as_float(u.x & 0xffff0000u);
    r.z = __uint_as_float(u.y << 16);
    r.w = __uint_as_float(u.y & 0xffff0000u);
    return r;
}

__device__ inline unsigned pkbf(float a, float b) {  // 2 fp32 -> packed bf16 (RTNE)
    unsigned ua = __float_as_uint(a), ub = __float_as_uint(b);
    unsigned ra = (ua + 0x7fffu + ((ua >> 16) & 1u)) >> 16;
    unsigned rb = (ub + 0x7fffu + ((ub >> 16) & 1u)) >> 16;
    return ra | (rb << 16);
}

// ---------------- CSR build ----------------

__global__ void k_count(const int* __restrict__ dst, int* __restrict__ deg) {
    int e = blockIdx.x * 256 + threadIdx.x;
    if (e < E_) atomicAdd(&deg[dst[e]], 1);
}

__global__ void k_dis(const int* __restrict__ deg, float* __restrict__ dis) {
    int i = blockIdx.x * 256 + threadIdx.x;
    if (i < N_) dis[i] = rsqrtf((float)deg[i] + 1.0f);
}

// single-block exclusive scan of deg -> row_ptr  (N=50000, 1024 threads x 49 chunk)
__global__ __launch_bounds__(1024) void k_scan(const int* __restrict__ deg,
                                               int* __restrict__ row_ptr) {
    __shared__ int a[1024];
    int t = threadIdx.x;
    const int CH = 49;
    int base = t * CH;
    int s = 0;
    for (int j = 0; j < CH; ++j) { int idx = base + j; if (idx < N_) s += deg[idx]; }
    a[t] = s;
    __syncthreads();
    for (int off = 1; off < 1024; off <<= 1) {
        int v = (t >= off) ? a[t - off] : 0;
        __syncthreads();
        a[t] += v;
        __syncthreads();
    }
    int run = a[t] - s;
    for (int j = 0; j < CH; ++j) {
        int idx = base + j;
        if (idx < N_) { row_ptr[idx] = run; run += deg[idx]; }
    }
    if (t == 0) row_ptr[N_] = E_;
}

__global__ void k_fill(const int* __restrict__ src, const int* __restrict__ dst,
                       const int* __restrict__ row_ptr, int* __restrict__ cursor,
                       int* __restrict__ csr_src) {
    int e = blockIdx.x * 256 + threadIdx.x;
    if (e < E_) {
        int d = dst[e];
        int pos = row_ptr[d] + atomicAdd(&cursor[d], 1);
        csr_src[pos] = src[e];
    }
}

// ---------------- GEMM: Hb = bf16( dis[row] * (X @ W) ) ----------------
// 64 rows x 128 cols per 256-thread block, fp32 accumulate, bf16 output.

__global__ __launch_bounds__(256) void k_gemm(const float* __restrict__ X,
                                              const float* __restrict__ W,
                                              const float* __restrict__ dis,
                                              uint4* __restrict__ Hb) {
    __shared__ float wlds[32 * 128];   // K-chunk of W: 16 KB
    __shared__ float xlds[64 * 36];    // 64 rows x 32 k, padded stride 36
    int t  = threadIdx.x;
    int r0 = blockIdx.x * 64;
    int cg = t & 15;    // col group: 8 cols each
    int rg = t >> 4;    // row group: 4 rows each

    float acc[4][8];
#pragma unroll
    for (int j = 0; j < 4; ++j)
#pragma unroll
        for (int c = 0; c < 8; ++c) acc[j][c] = 0.f;

    for (int k0 = 0; k0 < 128; k0 += 32) {
#pragma unroll
        for (int j = 0; j < 4; ++j) {
            int f = t + 256 * j;
            ((float4*)wlds)[f] = ((const float4*)(W + k0 * 128))[f];
        }
#pragma unroll
        for (int j = 0; j < 2; ++j) {
            int g   = t + 256 * j;
            int row = g >> 3;
            int kk4 = (g & 7) * 4;
            int gr  = r0 + row;
            float4 v = make_float4(0.f, 0.f, 0.f, 0.f);
            if (gr < N_) v = *(const float4*)(X + gr * 128 + k0 + kk4);
            xlds[row * 36 + kk4 + 0] = v.x;
            xlds[row * 36 + kk4 + 1] = v.y;
            xlds[row * 36 + kk4 + 2] = v.z;
            xlds[row * 36 + kk4 + 3] = v.w;
        }
        __syncthreads();
#pragma unroll
        for (int kk = 0; kk < 32; ++kk) {
            float4 w0 = *(const float4*)(wlds + kk * 128 + cg * 8);
            float4 w1 = *(const float4*)(wlds + kk * 128 + cg * 8 + 4);
#pragma unroll
            for (int j = 0; j < 4; ++j) {
                float xv = xlds[(rg * 4 + j) * 36 + kk];
                acc[j][0] += xv * w0.x; acc[j][1] += xv * w0.y;
                acc[j][2] += xv * w0.z; acc[j][3] += xv * w0.w;
                acc[j][4] += xv * w1.x; acc[j][5] += xv * w1.y;
                acc[j][6] += xv * w1.z; acc[j][7] += xv * w1.w;
            }
        }
        __syncthreads();
    }
#pragma unroll
    for (int j = 0; j < 4; ++j) {
        int r = r0 + rg * 4 + j;
        if (r < N_) {
            float dr = dis[r];
            uint4 o;
            o.x = pkbf(acc[j][0] * dr, acc[j][1] * dr);
            o.y = pkbf(acc[j][2] * dr, acc[j][3] * dr);
            o.z = pkbf(acc[j][4] * dr, acc[j][5] * dr);
            o.w = pkbf(acc[j][6] * dr, acc[j][7] * dr);
            Hb[r * 16 + cg] = o;   // row r, features cg*8..cg*8+7 (16 B)
        }
    }
}

// ---------------- Aggregation + fused BN stats ----------------
// AGG[n] = dis[n] * ( sum_{s in nbr(n)} Hb[s] + Hb[n] ) + bias
// 8 nodes per 256-thread block; 32 lanes/node, 4 features (uint2=4 bf16) each.

__global__ __launch_bounds__(256) void k_agg(const uint2* __restrict__ Hb,
                                             const int* __restrict__ row_ptr,
                                             const int* __restrict__ csr_src,
                                             const float* __restrict__ dis,
                                             const float* __restrict__ bias,
                                             float4* __restrict__ AGG,
                                             float* __restrict__ stats2) {
    int tid  = threadIdx.x;
    int sub  = tid >> 5;          // 0..7 : node within block
    int lane = tid & 31;          // feature group: features lane*4..lane*4+3
    int node = blockIdx.x * 8 + sub;   // 6250*8 == 50000 exactly

    int beg = row_ptr[node], end = row_ptr[node + 1];
    float4 acc = bcvt(Hb[node * 32 + lane]);   // self term (dis-scaled already)

    for (int c = beg; c < end; c += 32) {
        int m = end - c; if (m > 32) m = 32;
        int idx = (lane < m) ? csr_src[c + lane] : 0;
        int j = 0;
        for (; j + 4 <= m; j += 4) {
            int s0 = __shfl(idx, j, 32);
            int s1 = __shfl(idx, j + 1, 32);
            int s2 = __shfl(idx, j + 2, 32);
            int s3 = __shfl(idx, j + 3, 32);
            uint2 a0 = Hb[s0 * 32 + lane];
            uint2 a1 = Hb[s1 * 32 + lane];
            uint2 a2 = Hb[s2 * 32 + lane];
            uint2 a3 = Hb[s3 * 32 + lane];
            float4 f0 = bcvt(a0), f1 = bcvt(a1), f2 = bcvt(a2), f3 = bcvt(a3);
            acc.x += f0.x + f1.x + f2.x + f3.x;
            acc.y += f0.y + f1.y + f2.y + f3.y;
            acc.z += f0.z + f1.z + f2.z + f3.z;
            acc.w += f0.w + f1.w + f2.w + f3.w;
        }
        for (; j < m; ++j) {
            int s0 = __shfl(idx, j, 32);
            float4 f0 = bcvt(Hb[s0 * 32 + lane]);
            acc.x += f0.x; acc.y += f0.y; acc.z += f0.z; acc.w += f0.w;
        }
    }

    float dn = dis[node];
    float4 b4 = *(const float4*)(bias + lane * 4);
    float4 r;
    r.x = dn * acc.x + b4.x;
    r.y = dn * acc.y + b4.y;
    r.z = dn * acc.z + b4.z;
    r.w = dn * acc.w + b4.w;
    AGG[node * 32 + lane] = r;

    // fused BN stats: per-block reduce over the 8 nodes, then spread atomics
    __shared__ float4 buf[8][32];
    buf[sub][lane] = r;
    __syncthreads();
    if (tid < 128) {
        float s = 0.f, s2 = 0.f;
#pragma unroll
        for (int k = 0; k < 8; ++k) {
            float v = ((const float*)buf[k])[tid];   // feature tid of node k
            s += v; s2 += v * v;
        }
        float* st = stats2 + (blockIdx.x & 7) * 256;
        atomicAdd(&st[tid], s);
        atomicAdd(&st[128 + tid], s2);
    }
}

__global__ void k_bnfinal(const float* __restrict__ stats2,
                          const float* __restrict__ gamma,
                          const float* __restrict__ beta,
                          float* __restrict__ ab) {
    int f = threadIdx.x;  // 128
    float s = 0.f, s2 = 0.f;
#pragma unroll
    for (int k = 0; k < 8; ++k) {
        s  += stats2[k * 256 + f];
        s2 += stats2[k * 256 + 128 + f];
    }
    float mean = s * (1.0f / N_);
    float var  = s2 * (1.0f / N_) - mean * mean;
    float a = gamma[f] * rsqrtf(var + 1e-5f);
    ab[f]       = a;
    ab[128 + f] = beta[f] - mean * a;
}

// ---------------- Normalize + ReLU + residual (float4) ----------------

__global__ __launch_bounds__(256) void k_norm(const float* __restrict__ AGG,
                                              const float* __restrict__ res,
                                              const float* __restrict__ ab,
                                              float* __restrict__ OUT,
                                              int relu) {
    int i = blockIdx.x * 256 + threadIdx.x;  // float4 index
    if (i >= N_ * 32) return;
    int f4 = (i & 31) * 4;
    float4 v = ((const float4*)AGG)[i];
    float a0 = ab[f4], a1 = ab[f4 + 1], a2 = ab[f4 + 2], a3 = ab[f4 + 3];
    float b0 = ab[128 + f4], b1 = ab[128 + f4 + 1], b2 = ab[128 + f4 + 2], b3 = ab[128 + f4 + 3];
    v.x = a0 * v.x + b0; v.y = a1 * v.y + b1; v.z = a2 * v.z + b2; v.w = a3 * v.w + b3;
    if (relu) {
        v.x = fmaxf(v.x, 0.f); v.y = fmaxf(v.y, 0.f);
        v.z = fmaxf(v.z, 0.f); v.w = fmaxf(v.w, 0.f);
    }
    if (res) {
        float4 r = ((const float4*)res)[i];
        v.x += r.x; v.y += r.y; v.z += r.z; v.w += r.w;
    }
    ((float4*)OUT)[i] = v;
}

// ---------------- Launch ----------------

extern "C" void kernel_launch(void* const* d_in, const int* in_sizes, int n_in,
                              void* d_out, int out_size, void* d_ws, size_t ws_size,
                              hipStream_t stream) {
    const float* x      = (const float*)d_in[0];
    const int*   ei     = (const int*)d_in[1];
    const float* Ws     = (const float*)d_in[2];
    const float* bs     = (const float*)d_in[3];
    const float* gammas = (const float*)d_in[4];
    const float* betas  = (const float*)d_in[5];
    float* out = (float*)d_out;

    const int* src = ei;
    const int* dst = ei + E_;

    char* w = (char*)d_ws;
    int*   deg_int = (int*)(w + 0);           // N ints
    int*   cursor  = (int*)(w + 200000);      // N ints
    float* stats2  = (float*)(w + 400000);    // 3 layers x 8 copies x 256 floats = 24576 B
    float* ab      = (float*)(w + 424576);    // 2*D floats
    int*   row_ptr = (int*)(w + 425600);      // N+1 ints (200004 B, pad to 625616)
    float* dis     = (float*)(w + 625616);    // N floats
    int*   csr_src = (int*)(w + 825616);      // E ints
    uint4* Hb      = (uint4*)(w + 4025616);   // N*D bf16 = 12.8 MB
    float* B1      = (float*)(w + 16825616);  // N*D fp32
    float* B2      = (float*)(w + 42425616);  // N*D fp32

    // zero deg + cursor + stats2 region [0, 424576)
    hipMemsetAsync(d_ws, 0, 424576, stream);

    k_count<<<(E_ + 255) / 256, 256, 0, stream>>>(dst, deg_int);
    k_dis<<<(N_ + 255) / 256, 256, 0, stream>>>(deg_int, dis);
    k_scan<<<1, 1024, 0, stream>>>(deg_int, row_ptr);
    k_fill<<<(E_ + 255) / 256, 256, 0, stream>>>(src, dst, row_ptr, cursor, csr_src);

    // rotation:
    // L0: gemm(x  ->Hb), agg(Hb->B2, st0), norm(B2, null -> out), relu
    // L1: gemm(out->Hb), agg(Hb->B2, st1), norm(B2, out  -> B1),  relu
    // L2: gemm(B1 ->Hb), agg(Hb->B2, st2), norm(B2, B1   -> out), no relu
    const float* gemm_in[3]  = { x, out, B1 };
    const float* norm_res[3] = { nullptr, out, B1 };
    float*       norm_out[3] = { out, B1, out };
    int          relu[3]     = { 1, 1, 0 };

    for (int i = 0; i < L_; ++i) {
        k_gemm<<<(N_ + 63) / 64, 256, 0, stream>>>(gemm_in[i], Ws + i * D_ * D_, dis, Hb);
        k_agg<<<N_ / 8, 256, 0, stream>>>((const uint2*)Hb, row_ptr, csr_src, dis,
                                          bs + i * D_, (float4*)B2, stats2 + i * 2048);
        k_bnfinal<<<1, 128, 0, stream>>>(stats2 + i * 2048, gammas + i * D_, betas + i * D_, ab);
        k_norm<<<(N_ * 32 + 255) / 256, 256, 0, stream>>>(B2, norm_res[i], ab, norm_out[i], relu[i]);
    }
}

// Round 3
// 431.826 us; speedup vs baseline: 1.7341x; 1.1880x over previous
//
#include <hip/hip_runtime.h>
#include <hip/hip_bf16.h>

#define N_ 50000
#define E_ 800000
#define D_ 128
#define L_ 3

// ---------------- helpers ----------------

__device__ inline float4 bcvt(uint2 u) {   // 4 packed bf16 -> float4
    float4 r;
    r.x = __uint_as_float(u.x << 16);
    r.y = __uint_as_float(u.x & 0xffff0000u);
    r.z = __uint_as_float(u.y << 16);
    r.w = __uint_as_float(u.y & 0xffff0000u);
    return r;
}

__device__ inline unsigned pkbf(float a, float b) {  // 2 fp32 -> packed bf16 (RTNE)
    unsigned ua = __float_as_uint(a), ub = __float_as_uint(b);
    unsigned ra = (ua + 0x7fffu + ((ua >> 16) & 1u)) >> 16;
    unsigned rb = (ub + 0x7fffu + ((ub >> 16) & 1u)) >> 16;
    return ra | (rb << 16);
}

// ---------------- CSR build ----------------

__global__ void k_count(const int* __restrict__ dst, int* __restrict__ deg) {
    int e = blockIdx.x * 256 + threadIdx.x;
    if (e < E_) atomicAdd(&deg[dst[e]], 1);
}

// phase 1: per-block (1024 elems) inclusive scan; also writes dis[] and block sums
__global__ __launch_bounds__(1024) void k_scan1(const int* __restrict__ deg,
                                                int* __restrict__ linc,
                                                int* __restrict__ bsum,
                                                float* __restrict__ dis) {
    __shared__ int wsum[16];
    int t    = threadIdx.x;
    int lane = t & 63;
    int wid  = t >> 6;
    int i    = blockIdx.x * 1024 + t;
    int d    = (i < N_) ? deg[i] : 0;
    if (i < N_) dis[i] = rsqrtf((float)d + 1.0f);
    int v = d;
#pragma unroll
    for (int off = 1; off < 64; off <<= 1) {
        int u = __shfl_up(v, off);
        if (lane >= off) v += u;
    }
    if (lane == 63) wsum[wid] = v;
    __syncthreads();
    if (wid == 0) {
        int w = (lane < 16) ? wsum[lane] : 0;
#pragma unroll
        for (int off = 1; off < 16; off <<= 1) {
            int u = __shfl_up(w, off);
            if (lane >= off) w += u;
        }
        if (lane < 16) wsum[lane] = w;   // inclusive over waves
    }
    __syncthreads();
    int woff = (wid > 0) ? wsum[wid - 1] : 0;
    v += woff;
    if (i < N_) linc[i] = v;
    if (t == 1023) bsum[blockIdx.x] = v;   // block total (last elem's inclusive)
}

// phase 2: exclusive scan of 49 block sums (one wave)
__global__ void k_scan2(const int* __restrict__ bsum, int* __restrict__ boff) {
    int lane = threadIdx.x;   // 64 threads
    int v = (lane < 49) ? bsum[lane] : 0;
#pragma unroll
    for (int off = 1; off < 64; off <<= 1) {
        int u = __shfl_up(v, off);
        if (lane >= off) v += u;
    }
    if (lane < 49) boff[lane] = v - bsum[lane];   // exclusive
}

// phase 3: row_ptr[i+1] = linc[i] + boff[block];  row_ptr[0] = 0
__global__ __launch_bounds__(1024) void k_scan3(const int* __restrict__ linc,
                                                const int* __restrict__ boff,
                                                int* __restrict__ row_ptr) {
    int i = blockIdx.x * 1024 + threadIdx.x;
    if (i < N_) row_ptr[i + 1] = linc[i] + boff[blockIdx.x];
    if (i == 0) row_ptr[0] = 0;
}

__global__ void k_fill(const int* __restrict__ src, const int* __restrict__ dst,
                       const int* __restrict__ row_ptr, int* __restrict__ cursor,
                       int* __restrict__ csr_src) {
    int e = blockIdx.x * 256 + threadIdx.x;
    if (e < E_) {
        int d = dst[e];
        int pos = row_ptr[d] + atomicAdd(&cursor[d], 1);
        csr_src[pos] = src[e];
    }
}

// ---------------- GEMM: Hb = bf16( dis[row] * (X @ W) ) ----------------

__global__ __launch_bounds__(256) void k_gemm(const float* __restrict__ X,
                                              const float* __restrict__ W,
                                              const float* __restrict__ dis,
                                              uint4* __restrict__ Hb) {
    __shared__ float wlds[32 * 128];
    __shared__ float xlds[64 * 36];
    int t  = threadIdx.x;
    int r0 = blockIdx.x * 64;
    int cg = t & 15;
    int rg = t >> 4;

    float acc[4][8];
#pragma unroll
    for (int j = 0; j < 4; ++j)
#pragma unroll
        for (int c = 0; c < 8; ++c) acc[j][c] = 0.f;

    for (int k0 = 0; k0 < 128; k0 += 32) {
#pragma unroll
        for (int j = 0; j < 4; ++j) {
            int f = t + 256 * j;
            ((float4*)wlds)[f] = ((const float4*)(W + k0 * 128))[f];
        }
#pragma unroll
        for (int j = 0; j < 2; ++j) {
            int g   = t + 256 * j;
            int row = g >> 3;
            int kk4 = (g & 7) * 4;
            int gr  = r0 + row;
            float4 v = make_float4(0.f, 0.f, 0.f, 0.f);
            if (gr < N_) v = *(const float4*)(X + gr * 128 + k0 + kk4);
            xlds[row * 36 + kk4 + 0] = v.x;
            xlds[row * 36 + kk4 + 1] = v.y;
            xlds[row * 36 + kk4 + 2] = v.z;
            xlds[row * 36 + kk4 + 3] = v.w;
        }
        __syncthreads();
#pragma unroll
        for (int kk = 0; kk < 32; ++kk) {
            float4 w0 = *(const float4*)(wlds + kk * 128 + cg * 8);
            float4 w1 = *(const float4*)(wlds + kk * 128 + cg * 8 + 4);
#pragma unroll
            for (int j = 0; j < 4; ++j) {
                float xv = xlds[(rg * 4 + j) * 36 + kk];
                acc[j][0] += xv * w0.x; acc[j][1] += xv * w0.y;
                acc[j][2] += xv * w0.z; acc[j][3] += xv * w0.w;
                acc[j][4] += xv * w1.x; acc[j][5] += xv * w1.y;
                acc[j][6] += xv * w1.z; acc[j][7] += xv * w1.w;
            }
        }
        __syncthreads();
    }
#pragma unroll
    for (int j = 0; j < 4; ++j) {
        int r = r0 + rg * 4 + j;
        if (r < N_) {
            float dr = dis[r];
            uint4 o;
            o.x = pkbf(acc[j][0] * dr, acc[j][1] * dr);
            o.y = pkbf(acc[j][2] * dr, acc[j][3] * dr);
            o.z = pkbf(acc[j][4] * dr, acc[j][5] * dr);
            o.w = pkbf(acc[j][6] * dr, acc[j][7] * dr);
            Hb[r * 16 + cg] = o;
        }
    }
}

// ---------------- Aggregation + fused BN stats ----------------

__global__ __launch_bounds__(256) void k_agg(const uint2* __restrict__ Hb,
                                             const int* __restrict__ row_ptr,
                                             const int* __restrict__ csr_src,
                                             const float* __restrict__ dis,
                                             const float* __restrict__ bias,
                                             float4* __restrict__ AGG,
                                             float* __restrict__ stats2) {
    int tid  = threadIdx.x;
    int sub  = tid >> 5;
    int lane = tid & 31;
    int node = blockIdx.x * 8 + sub;

    int beg = row_ptr[node], end = row_ptr[node + 1];
    float4 acc = bcvt(Hb[node * 32 + lane]);   // self term (dis-scaled already)

    for (int c = beg; c < end; c += 32) {
        int m = end - c; if (m > 32) m = 32;
        int idx = (lane < m) ? csr_src[c + lane] : 0;
        int j = 0;
        for (; j + 4 <= m; j += 4) {
            int s0 = __shfl(idx, j, 32);
            int s1 = __shfl(idx, j + 1, 32);
            int s2 = __shfl(idx, j + 2, 32);
            int s3 = __shfl(idx, j + 3, 32);
            uint2 a0 = Hb[s0 * 32 + lane];
            uint2 a1 = Hb[s1 * 32 + lane];
            uint2 a2 = Hb[s2 * 32 + lane];
            uint2 a3 = Hb[s3 * 32 + lane];
            float4 f0 = bcvt(a0), f1 = bcvt(a1), f2 = bcvt(a2), f3 = bcvt(a3);
            acc.x += f0.x + f1.x + f2.x + f3.x;
            acc.y += f0.y + f1.y + f2.y + f3.y;
            acc.z += f0.z + f1.z + f2.z + f3.z;
            acc.w += f0.w + f1.w + f2.w + f3.w;
        }
        for (; j < m; ++j) {
            int s0 = __shfl(idx, j, 32);
            float4 f0 = bcvt(Hb[s0 * 32 + lane]);
            acc.x += f0.x; acc.y += f0.y; acc.z += f0.z; acc.w += f0.w;
        }
    }

    float dn = dis[node];
    float4 b4 = *(const float4*)(bias + lane * 4);
    float4 r;
    r.x = dn * acc.x + b4.x;
    r.y = dn * acc.y + b4.y;
    r.z = dn * acc.z + b4.z;
    r.w = dn * acc.w + b4.w;
    AGG[node * 32 + lane] = r;

    __shared__ float4 buf[8][32];
    buf[sub][lane] = r;
    __syncthreads();
    if (tid < 128) {
        float s = 0.f, s2 = 0.f;
#pragma unroll
        for (int k = 0; k < 8; ++k) {
            float v = ((const float*)buf[k])[tid];
            s += v; s2 += v * v;
        }
        float* st = stats2 + (blockIdx.x & 7) * 256;
        atomicAdd(&st[tid], s);
        atomicAdd(&st[128 + tid], s2);
    }
}

__global__ void k_bnfinal(const float* __restrict__ stats2,
                          const float* __restrict__ gamma,
                          const float* __restrict__ beta,
                          float* __restrict__ ab) {
    int f = threadIdx.x;  // 128
    float s = 0.f, s2 = 0.f;
#pragma unroll
    for (int k = 0; k < 8; ++k) {
        s  += stats2[k * 256 + f];
        s2 += stats2[k * 256 + 128 + f];
    }
    float mean = s * (1.0f / N_);
    float var  = s2 * (1.0f / N_) - mean * mean;
    float a = gamma[f] * rsqrtf(var + 1e-5f);
    ab[f]       = a;
    ab[128 + f] = beta[f] - mean * a;
}

// ---------------- Normalize + ReLU + residual (float4) ----------------

__global__ __launch_bounds__(256) void k_norm(const float* __restrict__ AGG,
                                              const float* __restrict__ res,
                                              const float* __restrict__ ab,
                                              float* __restrict__ OUT,
                                              int relu) {
    int i = blockIdx.x * 256 + threadIdx.x;
    if (i >= N_ * 32) return;
    int f4 = (i & 31) * 4;
    float4 v = ((const float4*)AGG)[i];
    float a0 = ab[f4], a1 = ab[f4 + 1], a2 = ab[f4 + 2], a3 = ab[f4 + 3];
    float b0 = ab[128 + f4], b1 = ab[128 + f4 + 1], b2 = ab[128 + f4 + 2], b3 = ab[128 + f4 + 3];
    v.x = a0 * v.x + b0; v.y = a1 * v.y + b1; v.z = a2 * v.z + b2; v.w = a3 * v.w + b3;
    if (relu) {
        v.x = fmaxf(v.x, 0.f); v.y = fmaxf(v.y, 0.f);
        v.z = fmaxf(v.z, 0.f); v.w = fmaxf(v.w, 0.f);
    }
    if (res) {
        float4 r = ((const float4*)res)[i];
        v.x += r.x; v.y += r.y; v.z += r.z; v.w += r.w;
    }
    ((float4*)OUT)[i] = v;
}

// ---------------- Launch ----------------

extern "C" void kernel_launch(void* const* d_in, const int* in_sizes, int n_in,
                              void* d_out, int out_size, void* d_ws, size_t ws_size,
                              hipStream_t stream) {
    const float* x      = (const float*)d_in[0];
    const int*   ei     = (const int*)d_in[1];
    const float* Ws     = (const float*)d_in[2];
    const float* bs     = (const float*)d_in[3];
    const float* gammas = (const float*)d_in[4];
    const float* betas  = (const float*)d_in[5];
    float* out = (float*)d_out;

    const int* src = ei;
    const int* dst = ei + E_;

    char* w = (char*)d_ws;
    int*   deg_int = (int*)(w + 0);           // N ints
    int*   cursor  = (int*)(w + 200000);      // N ints
    float* stats2  = (float*)(w + 400000);    // 3*8*256 floats
    float* ab      = (float*)(w + 424576);    // 2*D floats
    int*   row_ptr = (int*)(w + 425600);      // N+1 ints
    float* dis     = (float*)(w + 625616);    // N floats
    int*   csr_src = (int*)(w + 825616);      // E ints
    uint4* Hb      = (uint4*)(w + 4025616);   // N*D bf16
    float* B1      = (float*)(w + 16825616);  // N*D fp32
    float* B2      = (float*)(w + 42425616);  // N*D fp32

    // scan scratch: B1/B2 are dead until the layer loop — reuse them
    int* linc = (int*)B1;          // N ints
    int* bsum = (int*)B2;          // 49 ints
    int* boff = (int*)B2 + 64;     // 49 ints

    hipMemsetAsync(d_ws, 0, 424576, stream);   // deg + cursor + stats2

    k_count<<<(E_ + 255) / 256, 256, 0, stream>>>(dst, deg_int);
    k_scan1<<<49, 1024, 0, stream>>>(deg_int, linc, bsum, dis);
    k_scan2<<<1, 64, 0, stream>>>(bsum, boff);
    k_scan3<<<49, 1024, 0, stream>>>(linc, boff, row_ptr);
    k_fill<<<(E_ + 255) / 256, 256, 0, stream>>>(src, dst, row_ptr, cursor, csr_src);

    // rotation:
    // L0: gemm(x  ->Hb), agg(Hb->B2, st0), norm(B2, null -> out), relu
    // L1: gemm(out->Hb), agg(Hb->B2, st1), norm(B2, out  -> B1),  relu
    // L2: gemm(B1 ->Hb), agg(Hb->B2, st2), norm(B2, B1   -> out), no relu
    const float* gemm_in[3]  = { x, out, B1 };
    const float* norm_res[3] = { nullptr, out, B1 };
    float*       norm_out[3] = { out, B1, out };
    int          relu[3]     = { 1, 1, 0 };

    for (int i = 0; i < L_; ++i) {
        k_gemm<<<(N_ + 63) / 64, 256, 0, stream>>>(gemm_in[i], Ws + i * D_ * D_, dis, Hb);
        k_agg<<<N_ / 8, 256, 0, stream>>>((const uint2*)Hb, row_ptr, csr_src, dis,
                                          bs + i * D_, (float4*)B2, stats2 + i * 2048);
        k_bnfinal<<<1, 128, 0, stream>>>(stats2 + i * 2048, gammas + i * D_, betas + i * D_, ab);
        k_norm<<<(N_ * 32 + 255) / 256, 256, 0, stream>>>(B2, norm_res[i], ab, norm_out[i], relu[i]);
    }
}

// Round 4
// 363.879 us; speedup vs baseline: 2.0580x; 1.1867x over previous
//
#include <hip/hip_runtime.h>
#include <hip/hip_bf16.h>

#define N_ 50000
#define E_ 800000
#define D_ 128
#define L_ 3

// ---------------- helpers ----------------

__device__ inline float4 bcvt(uint2 u) {   // 4 packed bf16 -> float4
    float4 r;
    r.x = __uint_as_float(u.x << 16);
    r.y = __uint_as_float(u.x & 0xffff0000u);
    r.z = __uint_as_float(u.y << 16);
    r.w = __uint_as_float(u.y & 0xffff0000u);
    return r;
}

__device__ inline unsigned pkbf(float a, float b) {  // 2 fp32 -> packed bf16 (RTNE)
    unsigned ua = __float_as_uint(a), ub = __float_as_uint(b);
    unsigned ra = (ua + 0x7fffu + ((ua >> 16) & 1u)) >> 16;
    unsigned rb = (ub + 0x7fffu + ((ub >> 16) & 1u)) >> 16;
    return ra | (rb << 16);
}

// ---------------- CSR build ----------------

// count + capture within-row offset (the atomic's return value)
__global__ void k_count(const int* __restrict__ dst, int* __restrict__ deg,
                        int* __restrict__ offbuf) {
    int e = blockIdx.x * 256 + threadIdx.x;
    if (e < E_) offbuf[e] = atomicAdd(&deg[dst[e]], 1);
}

// phase 1: per-block (1024 elems) inclusive scan; also writes dis[] and block sums
__global__ __launch_bounds__(1024) void k_scan1(const int* __restrict__ deg,
                                                int* __restrict__ linc,
                                                int* __restrict__ bsum,
                                                float* __restrict__ dis) {
    __shared__ int wsum[16];
    int t    = threadIdx.x;
    int lane = t & 63;
    int wid  = t >> 6;
    int i    = blockIdx.x * 1024 + t;
    int d    = (i < N_) ? deg[i] : 0;
    if (i < N_) dis[i] = rsqrtf((float)d + 1.0f);
    int v = d;
#pragma unroll
    for (int off = 1; off < 64; off <<= 1) {
        int u = __shfl_up(v, off);
        if (lane >= off) v += u;
    }
    if (lane == 63) wsum[wid] = v;
    __syncthreads();
    if (wid == 0) {
        int w = (lane < 16) ? wsum[lane] : 0;
#pragma unroll
        for (int off = 1; off < 16; off <<= 1) {
            int u = __shfl_up(w, off);
            if (lane >= off) w += u;
        }
        if (lane < 16) wsum[lane] = w;
    }
    __syncthreads();
    int woff = (wid > 0) ? wsum[wid - 1] : 0;
    v += woff;
    if (i < N_) linc[i] = v;
    if (t == 1023) bsum[blockIdx.x] = v;
}

__global__ void k_scan2(const int* __restrict__ bsum, int* __restrict__ boff) {
    int lane = threadIdx.x;   // 64
    int v = (lane < 49) ? bsum[lane] : 0;
#pragma unroll
    for (int off = 1; off < 64; off <<= 1) {
        int u = __shfl_up(v, off);
        if (lane >= off) v += u;
    }
    if (lane < 49) boff[lane] = v - bsum[lane];
}

__global__ __launch_bounds__(1024) void k_scan3(const int* __restrict__ linc,
                                                const int* __restrict__ boff,
                                                int* __restrict__ row_ptr) {
    int i = blockIdx.x * 1024 + threadIdx.x;
    if (i < N_) row_ptr[i + 1] = linc[i] + boff[blockIdx.x];
    if (i == 0) row_ptr[0] = 0;
}

// atomic-free fill: position was precomputed in k_count
__global__ void k_fill(const int* __restrict__ src, const int* __restrict__ dst,
                       const int* __restrict__ row_ptr, const int* __restrict__ offbuf,
                       int* __restrict__ csr_src) {
    int e = blockIdx.x * 256 + threadIdx.x;
    if (e < E_) {
        int d = dst[e];
        csr_src[row_ptr[d] + offbuf[e]] = src[e];
    }
}

// ---------------- GEMM with fused input-normalize ----------------
// If st != null: x_row = relu(a*Xin + b) (+ res), side-written to xout; else x_row = Xin.
// Output: Hb = bf16( dis[row] * (x @ W) ).

__global__ __launch_bounds__(256) void k_gemm(const float* __restrict__ Xin,
                                              const float* __restrict__ W,
                                              const float* __restrict__ dis,
                                              uint4* __restrict__ Hb,
                                              const float* __restrict__ st,
                                              const float* __restrict__ gamma,
                                              const float* __restrict__ beta,
                                              const float* __restrict__ res,
                                              float* __restrict__ xout) {
    __shared__ float wlds[32 * 128];
    __shared__ float xlds[64 * 36];
    __shared__ float sab[256];
    int t  = threadIdx.x;
    int r0 = blockIdx.x * 64;
    int cg = t & 15;
    int rg = t >> 4;

    if (st) {
        if (t < 128) {
            float s = 0.f, s2 = 0.f;
#pragma unroll
            for (int k = 0; k < 8; ++k) {
                s  += st[k * 256 + t];
                s2 += st[k * 256 + 128 + t];
            }
            float mean = s * (1.0f / N_);
            float var  = s2 * (1.0f / N_) - mean * mean;
            float a = gamma[t] * rsqrtf(var + 1e-5f);
            sab[t]       = a;
            sab[128 + t] = beta[t] - mean * a;
        }
        __syncthreads();
    }

    float acc[4][8];
#pragma unroll
    for (int j = 0; j < 4; ++j)
#pragma unroll
        for (int c = 0; c < 8; ++c) acc[j][c] = 0.f;

    for (int k0 = 0; k0 < 128; k0 += 32) {
#pragma unroll
        for (int j = 0; j < 4; ++j) {
            int f = t + 256 * j;
            ((float4*)wlds)[f] = ((const float4*)(W + k0 * 128))[f];
        }
#pragma unroll
        for (int j = 0; j < 2; ++j) {
            int g   = t + 256 * j;
            int row = g >> 3;
            int kk4 = (g & 7) * 4;
            int gr  = r0 + row;
            float4 v = make_float4(0.f, 0.f, 0.f, 0.f);
            if (gr < N_) {
                v = *(const float4*)(Xin + gr * 128 + k0 + kk4);
                if (st) {
                    int f = k0 + kk4;
                    v.x = fmaxf(sab[f] * v.x + sab[128 + f], 0.f);
                    v.y = fmaxf(sab[f + 1] * v.y + sab[128 + f + 1], 0.f);
                    v.z = fmaxf(sab[f + 2] * v.z + sab[128 + f + 2], 0.f);
                    v.w = fmaxf(sab[f + 3] * v.w + sab[128 + f + 3], 0.f);
                    if (res) {
                        float4 rr = *(const float4*)(res + gr * 128 + f);
                        v.x += rr.x; v.y += rr.y; v.z += rr.z; v.w += rr.w;
                    }
                    *(float4*)(xout + gr * 128 + f) = v;
                }
            }
            xlds[row * 36 + kk4 + 0] = v.x;
            xlds[row * 36 + kk4 + 1] = v.y;
            xlds[row * 36 + kk4 + 2] = v.z;
            xlds[row * 36 + kk4 + 3] = v.w;
        }
        __syncthreads();
#pragma unroll
        for (int kk = 0; kk < 32; ++kk) {
            float4 w0 = *(const float4*)(wlds + kk * 128 + cg * 8);
            float4 w1 = *(const float4*)(wlds + kk * 128 + cg * 8 + 4);
#pragma unroll
            for (int j = 0; j < 4; ++j) {
                float xv = xlds[(rg * 4 + j) * 36 + kk];
                acc[j][0] += xv * w0.x; acc[j][1] += xv * w0.y;
                acc[j][2] += xv * w0.z; acc[j][3] += xv * w0.w;
                acc[j][4] += xv * w1.x; acc[j][5] += xv * w1.y;
                acc[j][6] += xv * w1.z; acc[j][7] += xv * w1.w;
            }
        }
        __syncthreads();
    }
#pragma unroll
    for (int j = 0; j < 4; ++j) {
        int r = r0 + rg * 4 + j;
        if (r < N_) {
            float dr = dis[r];
            uint4 o;
            o.x = pkbf(acc[j][0] * dr, acc[j][1] * dr);
            o.y = pkbf(acc[j][2] * dr, acc[j][3] * dr);
            o.z = pkbf(acc[j][4] * dr, acc[j][5] * dr);
            o.w = pkbf(acc[j][6] * dr, acc[j][7] * dr);
            Hb[r * 16 + cg] = o;
        }
    }
}

// ---------------- Aggregation + fused BN stats ----------------
// 16 nodes / 256-thread block; 16 lanes/node, 8 features (uint4 = 8 bf16) each.

__global__ __launch_bounds__(256) void k_agg(const uint4* __restrict__ Hb,
                                             const int* __restrict__ row_ptr,
                                             const int* __restrict__ csr_src,
                                             const float* __restrict__ dis,
                                             const float* __restrict__ bias,
                                             float4* __restrict__ AGG,
                                             float* __restrict__ stats2) {
    int tid  = threadIdx.x;
    int sub  = tid >> 4;          // 0..15 node in block
    int lane = tid & 15;          // feature group: 8 feats
    int node = blockIdx.x * 16 + sub;   // 3125*16 == 50000

    int beg = row_ptr[node], end = row_ptr[node + 1];
    uint4 su = Hb[node * 16 + lane];
    float4 acc0 = bcvt(make_uint2(su.x, su.y));
    float4 acc1 = bcvt(make_uint2(su.z, su.w));

    for (int c = beg; c < end; c += 16) {
        int m = end - c; if (m > 16) m = 16;
        int idx = (lane < m) ? csr_src[c + lane] : 0;
        int j = 0;
        for (; j + 4 <= m; j += 4) {
            int s0 = __shfl(idx, j, 16);
            int s1 = __shfl(idx, j + 1, 16);
            int s2 = __shfl(idx, j + 2, 16);
            int s3 = __shfl(idx, j + 3, 16);
            uint4 a0 = Hb[s0 * 16 + lane];
            uint4 a1 = Hb[s1 * 16 + lane];
            uint4 a2 = Hb[s2 * 16 + lane];
            uint4 a3 = Hb[s3 * 16 + lane];
            float4 f00 = bcvt(make_uint2(a0.x, a0.y)), f01 = bcvt(make_uint2(a0.z, a0.w));
            float4 f10 = bcvt(make_uint2(a1.x, a1.y)), f11 = bcvt(make_uint2(a1.z, a1.w));
            float4 f20 = bcvt(make_uint2(a2.x, a2.y)), f21 = bcvt(make_uint2(a2.z, a2.w));
            float4 f30 = bcvt(make_uint2(a3.x, a3.y)), f31 = bcvt(make_uint2(a3.z, a3.w));
            acc0.x += f00.x + f10.x + f20.x + f30.x;
            acc0.y += f00.y + f10.y + f20.y + f30.y;
            acc0.z += f00.z + f10.z + f20.z + f30.z;
            acc0.w += f00.w + f10.w + f20.w + f30.w;
            acc1.x += f01.x + f11.x + f21.x + f31.x;
            acc1.y += f01.y + f11.y + f21.y + f31.y;
            acc1.z += f01.z + f11.z + f21.z + f31.z;
            acc1.w += f01.w + f11.w + f21.w + f31.w;
        }
        for (; j < m; ++j) {
            int s0 = __shfl(idx, j, 16);
            uint4 a0 = Hb[s0 * 16 + lane];
            float4 f00 = bcvt(make_uint2(a0.x, a0.y)), f01 = bcvt(make_uint2(a0.z, a0.w));
            acc0.x += f00.x; acc0.y += f00.y; acc0.z += f00.z; acc0.w += f00.w;
            acc1.x += f01.x; acc1.y += f01.y; acc1.z += f01.z; acc1.w += f01.w;
        }
    }

    float dn = dis[node];
    float4 b0 = *(const float4*)(bias + lane * 8);
    float4 b1 = *(const float4*)(bias + lane * 8 + 4);
    float4 r0, r1;
    r0.x = dn * acc0.x + b0.x; r0.y = dn * acc0.y + b0.y;
    r0.z = dn * acc0.z + b0.z; r0.w = dn * acc0.w + b0.w;
    r1.x = dn * acc1.x + b1.x; r1.y = dn * acc1.y + b1.y;
    r1.z = dn * acc1.z + b1.z; r1.w = dn * acc1.w + b1.w;
    AGG[node * 32 + lane * 2]     = r0;
    AGG[node * 32 + lane * 2 + 1] = r1;

    __shared__ float sbuf[16][128];
    float4* sp = (float4*)&sbuf[sub][lane * 8];
    sp[0] = r0; sp[1] = r1;
    __syncthreads();
    if (tid < 128) {
        float s = 0.f, s2 = 0.f;
#pragma unroll
        for (int k = 0; k < 16; ++k) {
            float v = sbuf[k][tid];
            s += v; s2 += v * v;
        }
        float* stp = stats2 + (blockIdx.x & 7) * 256;
        atomicAdd(&stp[tid], s);
        atomicAdd(&stp[128 + tid], s2);
    }
}

// ---------------- Final normalize (layer 2): out = res + affine(AGG) ----------------

__global__ __launch_bounds__(256) void k_normF(const float4* __restrict__ AGG,
                                               const float4* __restrict__ res,
                                               const float* __restrict__ st,
                                               const float* __restrict__ gamma,
                                               const float* __restrict__ beta,
                                               float4* __restrict__ OUT) {
    __shared__ float sab[256];
    int t = threadIdx.x;
    if (t < 128) {
        float s = 0.f, s2 = 0.f;
#pragma unroll
        for (int k = 0; k < 8; ++k) {
            s  += st[k * 256 + t];
            s2 += st[k * 256 + 128 + t];
        }
        float mean = s * (1.0f / N_);
        float var  = s2 * (1.0f / N_) - mean * mean;
        float a = gamma[t] * rsqrtf(var + 1e-5f);
        sab[t]       = a;
        sab[128 + t] = beta[t] - mean * a;
    }
    __syncthreads();
    for (int i = blockIdx.x * 256 + t; i < N_ * 32; i += gridDim.x * 256) {
        int f4 = (i & 31) * 4;
        float4 v = AGG[i];
        float4 rr = res[i];
        v.x = sab[f4] * v.x + sab[128 + f4] + rr.x;
        v.y = sab[f4 + 1] * v.y + sab[128 + f4 + 1] + rr.y;
        v.z = sab[f4 + 2] * v.z + sab[128 + f4 + 2] + rr.z;
        v.w = sab[f4 + 3] * v.w + sab[128 + f4 + 3] + rr.w;
        OUT[i] = v;
    }
}

// ---------------- Launch ----------------

extern "C" void kernel_launch(void* const* d_in, const int* in_sizes, int n_in,
                              void* d_out, int out_size, void* d_ws, size_t ws_size,
                              hipStream_t stream) {
    const float* x      = (const float*)d_in[0];
    const int*   ei     = (const int*)d_in[1];
    const float* Ws     = (const float*)d_in[2];
    const float* bs     = (const float*)d_in[3];
    const float* gammas = (const float*)d_in[4];
    const float* betas  = (const float*)d_in[5];
    float* out = (float*)d_out;

    const int* src = ei;
    const int* dst = ei + E_;

    char* w = (char*)d_ws;
    int*   deg     = (int*)(w + 0);            // N ints            [0, 200000)
    float* stats2  = (float*)(w + 200000);     // 3*2048 floats     [200000, 224576)
    int*   row_ptr = (int*)(w + 224576);       // N+1 ints          [224576, 424592)
    float* dis     = (float*)(w + 424592);     // N floats          [424592, 624592)
    int*   offbuf  = (int*)(w + 624592);       // E ints            [624592, 3824592)
    int*   csr_src = (int*)(w + 3824592);      // E ints            [3824592, 7024592)
    uint4* Hb      = (uint4*)(w + 7024640);    // N*D bf16 12.8 MB  [7024640, 19824640)
    float* XB      = (float*)(w + 19824640);   // N*D fp32 25.6 MB  [19824640, 45424640)
    float* AGG     = out;                      // AGG lives in d_out

    // scan scratch reuses XB (dead until layer loop)
    int* linc = (int*)XB;
    int* bsum = (int*)XB + N_;
    int* boff = (int*)XB + N_ + 64;

    hipMemsetAsync(d_ws, 0, 224576, stream);   // deg + stats2

    k_count<<<(E_ + 255) / 256, 256, 0, stream>>>(dst, deg, offbuf);
    k_scan1<<<49, 1024, 0, stream>>>(deg, linc, bsum, dis);
    k_scan2<<<1, 64, 0, stream>>>(bsum, boff);
    k_scan3<<<49, 1024, 0, stream>>>(linc, boff, row_ptr);
    k_fill<<<(E_ + 255) / 256, 256, 0, stream>>>(src, dst, row_ptr, offbuf, csr_src);

    const int GG = (N_ + 63) / 64;
    // L0: gemm(x raw) -> Hb ; agg -> AGG(d_out), st0
    k_gemm<<<GG, 256, 0, stream>>>(x, Ws, dis, Hb,
                                   nullptr, nullptr, nullptr, nullptr, nullptr);
    k_agg<<<N_ / 16, 256, 0, stream>>>(Hb, row_ptr, csr_src, dis, bs,
                                       (float4*)AGG, stats2);
    // L1: gemm(AGG0 | affine0+relu -> x1 -> XB) -> Hb ; agg -> AGG, st1
    k_gemm<<<GG, 256, 0, stream>>>(AGG, Ws + D_ * D_, dis, Hb,
                                   stats2, gammas, betas, nullptr, XB);
    k_agg<<<N_ / 16, 256, 0, stream>>>(Hb, row_ptr, csr_src, dis, bs + D_,
                                       (float4*)AGG, stats2 + 2048);
    // L2: gemm(AGG1 | affine1+relu + res XB -> x2 -> XB) -> Hb ; agg -> AGG, st2
    k_gemm<<<GG, 256, 0, stream>>>(AGG, Ws + 2 * D_ * D_, dis, Hb,
                                   stats2 + 2048, gammas + D_, betas + D_, XB, XB);
    k_agg<<<N_ / 16, 256, 0, stream>>>(Hb, row_ptr, csr_src, dis, bs + 2 * D_,
                                       (float4*)AGG, stats2 + 4096);
    // final: out = x2 + affine2(AGG2)   (in-place on d_out)
    k_normF<<<512, 256, 0, stream>>>((const float4*)AGG, (const float4*)XB,
                                     stats2 + 4096, gammas + 2 * D_, betas + 2 * D_,
                                     (float4*)out);
}

// Round 5
// 312.663 us; speedup vs baseline: 2.3951x; 1.1638x over previous
//
#include <hip/hip_runtime.h>
#include <hip/hip_bf16.h>
#include <hip/hip_fp16.h>

#define N_ 50000
#define E_ 800000
#define D_ 128
#define L_ 3

typedef _Float16 half8 __attribute__((ext_vector_type(8)));
typedef float f32x4 __attribute__((ext_vector_type(4)));

// ---------------- helpers ----------------

__device__ inline float4 hcvt(uint2 u) {   // 4 packed fp16 -> float4
    __half2 h0 = *(__half2*)&u.x;
    __half2 h1 = *(__half2*)&u.y;
    float2 f0 = __half22float2(h0);
    float2 f1 = __half22float2(h1);
    return make_float4(f0.x, f0.y, f1.x, f1.y);
}

__device__ inline unsigned pkh(float a, float b) {  // 2 fp32 -> packed fp16 (RTNE)
    __half2 h = __floats2half2_rn(a, b);
    return *(unsigned*)&h;
}

__device__ inline unsigned short pkh1(float a) {
    _Float16 h = (_Float16)a;
    return *(unsigned short*)&h;
}

// ---------------- CSR build ----------------

__global__ void k_count(const int* __restrict__ dst, int* __restrict__ deg,
                        int* __restrict__ offbuf) {
    int e = blockIdx.x * 256 + threadIdx.x;
    if (e < E_) offbuf[e] = atomicAdd(&deg[dst[e]], 1);
}

__global__ __launch_bounds__(1024) void k_scan1(const int* __restrict__ deg,
                                                int* __restrict__ linc,
                                                int* __restrict__ bsum,
                                                float* __restrict__ dis) {
    __shared__ int wsum[16];
    int t    = threadIdx.x;
    int lane = t & 63;
    int wid  = t >> 6;
    int i    = blockIdx.x * 1024 + t;
    int d    = (i < N_) ? deg[i] : 0;
    if (i < N_) dis[i] = rsqrtf((float)d + 1.0f);
    int v = d;
#pragma unroll
    for (int off = 1; off < 64; off <<= 1) {
        int u = __shfl_up(v, off);
        if (lane >= off) v += u;
    }
    if (lane == 63) wsum[wid] = v;
    __syncthreads();
    if (wid == 0) {
        int w = (lane < 16) ? wsum[lane] : 0;
#pragma unroll
        for (int off = 1; off < 16; off <<= 1) {
            int u = __shfl_up(w, off);
            if (lane >= off) w += u;
        }
        if (lane < 16) wsum[lane] = w;
    }
    __syncthreads();
    int woff = (wid > 0) ? wsum[wid - 1] : 0;
    v += woff;
    if (i < N_) linc[i] = v;
    if (t == 1023) bsum[blockIdx.x] = v;
}

__global__ void k_scan2(const int* __restrict__ bsum, int* __restrict__ boff) {
    int lane = threadIdx.x;   // 64
    int v = (lane < 49) ? bsum[lane] : 0;
#pragma unroll
    for (int off = 1; off < 64; off <<= 1) {
        int u = __shfl_up(v, off);
        if (lane >= off) v += u;
    }
    if (lane < 49) boff[lane] = v - bsum[lane];
}

__global__ __launch_bounds__(1024) void k_scan3(const int* __restrict__ linc,
                                                const int* __restrict__ boff,
                                                int* __restrict__ row_ptr) {
    int i = blockIdx.x * 1024 + threadIdx.x;
    if (i < N_) row_ptr[i + 1] = linc[i] + boff[blockIdx.x];
    if (i == 0) row_ptr[0] = 0;
}

__global__ void k_fill(const int* __restrict__ src, const int* __restrict__ dst,
                       const int* __restrict__ row_ptr, const int* __restrict__ offbuf,
                       int* __restrict__ csr_src) {
    int e = blockIdx.x * 256 + threadIdx.x;
    if (e < E_) {
        int d = dst[e];
        csr_src[row_ptr[d] + offbuf[e]] = src[e];
    }
}

// ---------------- W precompute: fp32 [k][n] -> fp16 transposed [n][k] ----------------

__global__ __launch_bounds__(256) void k_prew(const float* __restrict__ Ws,
                                              unsigned short* __restrict__ Wb) {
    int l = blockIdx.x;
    const float* Wl = Ws + l * 16384;
    unsigned short* Wo = Wb + l * 16384;
    for (int i = threadIdx.x; i < 16384; i += 256) {
        int n = i >> 7, k = i & 127;          // consecutive i -> consecutive k: coalesced writes
        Wo[n * 128 + k] = pkh1(Wl[k * 128 + n]);
    }
}

// ---------------- MFMA GEMM with fused input-normalize ----------------
// If st != null: x_row = relu(a*Xin + b) (+ res), side-written to xout (fp32); else x = Xin.
// Output: Hb = fp16( dis[row] * (x @ W) ).  64 rows x 128 cols per 256-thread block.

__global__ __launch_bounds__(256) void k_gemm(const float* __restrict__ Xin,
                                              const unsigned short* __restrict__ Wb,
                                              const float* __restrict__ dis,
                                              uint4* __restrict__ Hb,
                                              const float* __restrict__ st,
                                              const float* __restrict__ gamma,
                                              const float* __restrict__ beta,
                                              const float* __restrict__ res,
                                              float* __restrict__ xout) {
    __shared__ unsigned short wt[128 * 136];   // W^T fp16, padded stride 136
    __shared__ unsigned short xb[64 * 136];    // X tile fp16 (reused for C repack)
    __shared__ float sab[256];
    int t  = threadIdx.x;
    int r0 = blockIdx.x * 64;

    if (st) {
        if (t < 128) {
            float s = 0.f, s2 = 0.f;
#pragma unroll
            for (int k = 0; k < 8; ++k) {
                s  += st[k * 256 + t];
                s2 += st[k * 256 + 128 + t];
            }
            float mean = s * (1.0f / N_);
            float var  = s2 * (1.0f / N_) - mean * mean;
            float a = gamma[t] * rsqrtf(var + 1e-5f);
            sab[t]       = a;
            sab[128 + t] = beta[t] - mean * a;
        }
        __syncthreads();
    }

    // stage W^T (2048 uint4, 8 per thread, coalesced)
#pragma unroll
    for (int j = 0; j < 8; ++j) {
        int i = t + 256 * j;
        int row = i >> 4, c16 = i & 15;
        *(uint4*)&wt[row * 136 + c16 * 8] = ((const uint4*)Wb)[i];
    }
    // stage X: fp32 -> (affine/relu/res) -> fp16 LDS (+ fp32 side-write)
#pragma unroll
    for (int j = 0; j < 8; ++j) {
        int g   = t + 256 * j;          // float4 index among 64*32
        int row = g >> 5;
        int c4  = (g & 31) * 4;
        int gr  = r0 + row;
        float4 v = make_float4(0.f, 0.f, 0.f, 0.f);
        if (gr < N_) {
            v = *(const float4*)(Xin + gr * 128 + c4);
            if (st) {
                v.x = fmaxf(sab[c4] * v.x + sab[128 + c4], 0.f);
                v.y = fmaxf(sab[c4 + 1] * v.y + sab[128 + c4 + 1], 0.f);
                v.z = fmaxf(sab[c4 + 2] * v.z + sab[128 + c4 + 2], 0.f);
                v.w = fmaxf(sab[c4 + 3] * v.w + sab[128 + c4 + 3], 0.f);
                if (res) {
                    float4 rr = *(const float4*)(res + gr * 128 + c4);
                    v.x += rr.x; v.y += rr.y; v.z += rr.z; v.w += rr.w;
                }
                *(float4*)(xout + gr * 128 + c4) = v;
            }
        }
        uint2 p;
        p.x = pkh(v.x, v.y);
        p.y = pkh(v.z, v.w);
        *(uint2*)&xb[row * 136 + c4] = p;
    }
    __syncthreads();

    int wv   = t >> 6;
    int lane = t & 63;
    int ln   = lane & 15;
    int quad = lane >> 4;

    const unsigned short* arow = &xb[(wv * 16 + ln) * 136 + quad * 8];
    half8 af[4];
#pragma unroll
    for (int ks = 0; ks < 4; ++ks) af[ks] = *(const half8*)(arow + ks * 32);

    f32x4 acc[8];
#pragma unroll
    for (int ct = 0; ct < 8; ++ct) acc[ct] = (f32x4){0.f, 0.f, 0.f, 0.f};

#pragma unroll
    for (int ct = 0; ct < 8; ++ct) {
        const unsigned short* wp = &wt[(ct * 16 + ln) * 136 + quad * 8];
#pragma unroll
        for (int ks = 0; ks < 4; ++ks) {
            half8 bf = *(const half8*)(wp + ks * 32);
            acc[ct] = __builtin_amdgcn_mfma_f32_16x16x32_f16(af[ks], bf, acc[ct], 0, 0, 0);
        }
    }

    // epilogue: dis-scale, fp16, repack via LDS (xb reused), coalesced uint4 store
    float dr[4];
#pragma unroll
    for (int reg = 0; reg < 4; ++reg) {
        int r = r0 + wv * 16 + quad * 4 + reg;
        dr[reg] = dis[r < N_ ? r : (N_ - 1)];
    }
#pragma unroll
    for (int ct = 0; ct < 8; ++ct) {
#pragma unroll
        for (int reg = 0; reg < 4; ++reg) {
            int lrow = wv * 16 + quad * 4 + reg;
            xb[lrow * 136 + ct * 16 + ln] = pkh1(acc[ct][reg] * dr[reg]);
        }
    }
    __syncthreads();
#pragma unroll
    for (int j = 0; j < 4; ++j) {
        int i = t + 256 * j;       // uint4 among 64*16
        int row = i >> 4, c16 = i & 15;
        int gr = r0 + row;
        if (gr < N_) Hb[gr * 16 + c16] = *(uint4*)&xb[row * 136 + c16 * 8];
    }
}

// ---------------- Aggregation + fused BN stats (fp16 gathers) ----------------

__global__ __launch_bounds__(256) void k_agg(const uint4* __restrict__ Hb,
                                             const int* __restrict__ row_ptr,
                                             const int* __restrict__ csr_src,
                                             const float* __restrict__ dis,
                                             const float* __restrict__ bias,
                                             float4* __restrict__ AGG,
                                             float* __restrict__ stats2) {
    int tid  = threadIdx.x;
    int sub  = tid >> 4;          // 0..15 node in block
    int lane = tid & 15;          // feature group: 8 feats
    int node = blockIdx.x * 16 + sub;

    int beg = row_ptr[node], end = row_ptr[node + 1];
    uint4 su = Hb[node * 16 + lane];
    float4 acc0 = hcvt(make_uint2(su.x, su.y));
    float4 acc1 = hcvt(make_uint2(su.z, su.w));

    for (int c = beg; c < end; c += 16) {
        int m = end - c; if (m > 16) m = 16;
        int idx = (lane < m) ? csr_src[c + lane] : 0;
        int j = 0;
        for (; j + 4 <= m; j += 4) {
            int s0 = __shfl(idx, j, 16);
            int s1 = __shfl(idx, j + 1, 16);
            int s2 = __shfl(idx, j + 2, 16);
            int s3 = __shfl(idx, j + 3, 16);
            uint4 a0 = Hb[s0 * 16 + lane];
            uint4 a1 = Hb[s1 * 16 + lane];
            uint4 a2 = Hb[s2 * 16 + lane];
            uint4 a3 = Hb[s3 * 16 + lane];
            float4 f00 = hcvt(make_uint2(a0.x, a0.y)), f01 = hcvt(make_uint2(a0.z, a0.w));
            float4 f10 = hcvt(make_uint2(a1.x, a1.y)), f11 = hcvt(make_uint2(a1.z, a1.w));
            float4 f20 = hcvt(make_uint2(a2.x, a2.y)), f21 = hcvt(make_uint2(a2.z, a2.w));
            float4 f30 = hcvt(make_uint2(a3.x, a3.y)), f31 = hcvt(make_uint2(a3.z, a3.w));
            acc0.x += f00.x + f10.x + f20.x + f30.x;
            acc0.y += f00.y + f10.y + f20.y + f30.y;
            acc0.z += f00.z + f10.z + f20.z + f30.z;
            acc0.w += f00.w + f10.w + f20.w + f30.w;
            acc1.x += f01.x + f11.x + f21.x + f31.x;
            acc1.y += f01.y + f11.y + f21.y + f31.y;
            acc1.z += f01.z + f11.z + f21.z + f31.z;
            acc1.w += f01.w + f11.w + f21.w + f31.w;
        }
        for (; j < m; ++j) {
            int s0 = __shfl(idx, j, 16);
            uint4 a0 = Hb[s0 * 16 + lane];
            float4 f00 = hcvt(make_uint2(a0.x, a0.y)), f01 = hcvt(make_uint2(a0.z, a0.w));
            acc0.x += f00.x; acc0.y += f00.y; acc0.z += f00.z; acc0.w += f00.w;
            acc1.x += f01.x; acc1.y += f01.y; acc1.z += f01.z; acc1.w += f01.w;
        }
    }

    float dn = dis[node];
    float4 b0 = *(const float4*)(bias + lane * 8);
    float4 b1 = *(const float4*)(bias + lane * 8 + 4);
    float4 r0, r1;
    r0.x = dn * acc0.x + b0.x; r0.y = dn * acc0.y + b0.y;
    r0.z = dn * acc0.z + b0.z; r0.w = dn * acc0.w + b0.w;
    r1.x = dn * acc1.x + b1.x; r1.y = dn * acc1.y + b1.y;
    r1.z = dn * acc1.z + b1.z; r1.w = dn * acc1.w + b1.w;
    AGG[node * 32 + lane * 2]     = r0;
    AGG[node * 32 + lane * 2 + 1] = r1;

    __shared__ float sbuf[16][128];
    float4* sp = (float4*)&sbuf[sub][lane * 8];
    sp[0] = r0; sp[1] = r1;
    __syncthreads();
    if (tid < 128) {
        float s = 0.f, s2 = 0.f;
#pragma unroll
        for (int k = 0; k < 16; ++k) {
            float v = sbuf[k][tid];
            s += v; s2 += v * v;
        }
        float* stp = stats2 + (blockIdx.x & 7) * 256;
        atomicAdd(&stp[tid], s);
        atomicAdd(&stp[128 + tid], s2);
    }
}

// ---------------- Final normalize (layer 2): out = res + affine(AGG) ----------------

__global__ __launch_bounds__(256) void k_normF(const float4* __restrict__ AGG,
                                               const float4* __restrict__ res,
                                               const float* __restrict__ st,
                                               const float* __restrict__ gamma,
                                               const float* __restrict__ beta,
                                               float4* __restrict__ OUT) {
    __shared__ float sab[256];
    int t = threadIdx.x;
    if (t < 128) {
        float s = 0.f, s2 = 0.f;
#pragma unroll
        for (int k = 0; k < 8; ++k) {
            s  += st[k * 256 + t];
            s2 += st[k * 256 + 128 + t];
        }
        float mean = s * (1.0f / N_);
        float var  = s2 * (1.0f / N_) - mean * mean;
        float a = gamma[t] * rsqrtf(var + 1e-5f);
        sab[t]       = a;
        sab[128 + t] = beta[t] - mean * a;
    }
    __syncthreads();
    for (int i = blockIdx.x * 256 + t; i < N_ * 32; i += gridDim.x * 256) {
        int f4 = (i & 31) * 4;
        float4 v = AGG[i];
        float4 rr = res[i];
        v.x = sab[f4] * v.x + sab[128 + f4] + rr.x;
        v.y = sab[f4 + 1] * v.y + sab[128 + f4 + 1] + rr.y;
        v.z = sab[f4 + 2] * v.z + sab[128 + f4 + 2] + rr.z;
        v.w = sab[f4 + 3] * v.w + sab[128 + f4 + 3] + rr.w;
        OUT[i] = v;
    }
}

// ---------------- Launch ----------------

extern "C" void kernel_launch(void* const* d_in, const int* in_sizes, int n_in,
                              void* d_out, int out_size, void* d_ws, size_t ws_size,
                              hipStream_t stream) {
    const float* x      = (const float*)d_in[0];
    const int*   ei     = (const int*)d_in[1];
    const float* Ws     = (const float*)d_in[2];
    const float* bs     = (const float*)d_in[3];
    const float* gammas = (const float*)d_in[4];
    const float* betas  = (const float*)d_in[5];
    float* out = (float*)d_out;

    const int* src = ei;
    const int* dst = ei + E_;

    char* w = (char*)d_ws;
    int*   deg     = (int*)(w + 0);            // N ints            [0, 200000)
    float* stats2  = (float*)(w + 200000);     // 3*2048 floats     [200000, 224576)
    int*   row_ptr = (int*)(w + 224576);       // N+1 ints          [224576, 424592)
    float* dis     = (float*)(w + 424592);     // N floats          [424592, 624592)
    int*   offbuf  = (int*)(w + 624592);       // E ints            [624592, 3824592)  (dead after k_fill)
    int*   csr_src = (int*)(w + 3824592);      // E ints            [3824592, 7024592)
    uint4* Hb      = (uint4*)(w + 7024640);    // N*D fp16 12.8 MB  [7024640, 19824640)
    float* XB      = (float*)(w + 19824640);   // N*D fp32 25.6 MB  [19824640, 45424640)
    unsigned short* Wb = (unsigned short*)offbuf;  // 3*128*128 fp16 = 98 KB, reuses dead offbuf
    float* AGG     = out;                      // AGG lives in d_out

    // scan scratch reuses XB (dead until layer loop)
    int* linc = (int*)XB;
    int* bsum = (int*)XB + N_;
    int* boff = (int*)XB + N_ + 64;

    hipMemsetAsync(d_ws, 0, 224576, stream);   // deg + stats2

    k_count<<<(E_ + 255) / 256, 256, 0, stream>>>(dst, deg, offbuf);
    k_scan1<<<49, 1024, 0, stream>>>(deg, linc, bsum, dis);
    k_scan2<<<1, 64, 0, stream>>>(bsum, boff);
    k_scan3<<<49, 1024, 0, stream>>>(linc, boff, row_ptr);
    k_fill<<<(E_ + 255) / 256, 256, 0, stream>>>(src, dst, row_ptr, offbuf, csr_src);
    k_prew<<<3, 256, 0, stream>>>(Ws, Wb);     // after k_fill: offbuf is dead now

    const int GG = (N_ + 63) / 64;   // 782
    // L0: gemm(x raw) -> Hb ; agg -> AGG(d_out), st0
    k_gemm<<<GG, 256, 0, stream>>>(x, Wb, dis, Hb,
                                   nullptr, nullptr, nullptr, nullptr, nullptr);
    k_agg<<<N_ / 16, 256, 0, stream>>>(Hb, row_ptr, csr_src, dis, bs,
                                       (float4*)AGG, stats2);
    // L1: gemm(AGG0 | affine0+relu -> x1 -> XB) -> Hb ; agg -> AGG, st1
    k_gemm<<<GG, 256, 0, stream>>>(AGG, Wb + 16384, dis, Hb,
                                   stats2, gammas, betas, nullptr, XB);
    k_agg<<<N_ / 16, 256, 0, stream>>>(Hb, row_ptr, csr_src, dis, bs + D_,
                                       (float4*)AGG, stats2 + 2048);
    // L2: gemm(AGG1 | affine1+relu + res XB -> x2 -> XB) -> Hb ; agg -> AGG, st2
    k_gemm<<<GG, 256, 0, stream>>>(AGG, Wb + 32768, dis, Hb,
                                   stats2 + 2048, gammas + D_, betas + D_, XB, XB);
    k_agg<<<N_ / 16, 256, 0, stream>>>(Hb, row_ptr, csr_src, dis, bs + 2 * D_,
                                       (float4*)AGG, stats2 + 4096);
    // final: out = x2 + affine2(AGG2)   (in-place on d_out)
    k_normF<<<512, 256, 0, stream>>>((const float4*)AGG, (const float4*)XB,
                                     stats2 + 4096, gammas + 2 * D_, betas + 2 * D_,
                                     (float4*)out);
}